// Round 3
// baseline (556.549 us; speedup 1.0000x reference)
//
#include <hip/hip_runtime.h>
#include <hip/hip_bf16.h>
#include <hip/hip_fp16.h>

// KAN layer = fp16 MFMA GEMM over g-major expanded K: k = p*2048 + i.
// plane p=0: feature x, weight bw; planes p=1..8: feature relu(x-kn[p-1]),
// weight 0.1*sw[o,i,p-1]. Features derived in-register from a per-i-block
// x-tile (no A image).
// R7: triple-buffered W tiles, prefetch distance 2, counted vmcnt (never 0
// in main loop), raw s_barrier, setprio(1) around compute.
// R8: (a) relu via __builtin_elementwise_max -> guaranteed v_pk_add/max_f16
// (8 ops/frag, was lowering scalar); (b) MFMA 32x32x16_f16 -> half the MFMA
// instructions per plane (issue slots) at the faster 32x32 pipe rate.
#define BATCH 4096
#define IN_F  2048
#define OUT_F 2048
#define NPLANE 9
#define KDIM  (IN_F * NPLANE)        // 18432
#define MN    ((size_t)BATCH * OUT_F)

typedef __attribute__((ext_vector_type(8)))  _Float16 f16x8;
typedef __attribute__((ext_vector_type(2)))  _Float16 f16x2;
typedef __attribute__((ext_vector_type(4)))  float    f32x4;
typedef __attribute__((ext_vector_type(16))) float    f32x16;

#define WAITVM(N) { asm volatile("s_waitcnt vmcnt(" #N ")" ::: "memory"); \
                    __builtin_amdgcn_sched_barrier(0); }

// ---------------- prep: x fp32 -> fp16 image [b][i] ----------------
__global__ __launch_bounds__(256) void prep_X(const float* __restrict__ x,
                                              _Float16* __restrict__ X) {
  const size_t idx = ((size_t)blockIdx.x * 256 + threadIdx.x) * 8;
  const float4* v = (const float4*)(x + idx);
  float4 a = v[0], b = v[1];
  f16x8 o;
  o[0]=(_Float16)a.x; o[1]=(_Float16)a.y; o[2]=(_Float16)a.z; o[3]=(_Float16)a.w;
  o[4]=(_Float16)b.x; o[5]=(_Float16)b.y; o[6]=(_Float16)b.z; o[7]=(_Float16)b.w;
  *(f16x8*)(X + idx) = o;
}

// ---------------- prep: bw + sw -> W image [o][p*2048+i], all 9 planes ----------------
__global__ __launch_bounds__(256) void prep_W(const float* __restrict__ bw,
                                              const float* __restrict__ sw,
                                              _Float16* __restrict__ W) {
  const int o  = blockIdx.x;          // 2048 blocks
  const int i0 = threadIdx.x * 8;     // i-chunk

  const float4* s = (const float4*)(sw + ((size_t)o * IN_F + i0) * 8);
  float4 qv[16];
#pragma unroll
  for (int k = 0; k < 16; ++k) qv[k] = s[k];
  const float* q = (const float*)qv;  // q[j*8 + g] = sw[o, i0+j, g]

  _Float16* base = W + (size_t)o * KDIM + i0;

  // plane 0: base weight
  const float4* b4 = (const float4*)(bw + (size_t)o * IN_F + i0);
  float4 b0 = b4[0], b1 = b4[1];
  f16x8 h0;
  h0[0]=(_Float16)b0.x; h0[1]=(_Float16)b0.y; h0[2]=(_Float16)b0.z; h0[3]=(_Float16)b0.w;
  h0[4]=(_Float16)b1.x; h0[5]=(_Float16)b1.y; h0[6]=(_Float16)b1.z; h0[7]=(_Float16)b1.w;
  *(f16x8*)base = h0;

  // planes 1..8: 0.1 * sw[o, i, g]
#pragma unroll
  for (int g = 0; g < 8; ++g) {
    f16x8 h;
#pragma unroll
    for (int j = 0; j < 8; ++j)
      h[j] = (_Float16)(0.1f * q[j * 8 + g]);
    *(f16x8*)(base + (g + 1) * IN_F) = h;
  }
}

// ---------------- GEMM ----------------
#define BM 128
#define BN 128
#define BK 64

// relu(x - k), packed: 4x v_pk_add_f16 + 4x v_pk_max_f16
__device__ inline f16x8 relu_shift(f16x8 x, _Float16 kg) {
  f16x8 d = x - kg;
  f16x8 z = {};
  return __builtin_elementwise_max(d, z);
}

// Pipeline (per wave, 4 global_load_lds per tile):
//   step s = (ib, p) computes plane p from Ws[p%3]; issues tile s+2 into
//   Ws[(p+2)%3]; X(ib+1) issued at p==1 (after plane-0 barrier, Xs dead).
//   End-of-step wait leaves the newest prefetch in flight:
//     steady: vmcnt(4); p=1,2: vmcnt(8) (X group sits in the FIFO);
//     ib=31 tail: vmcnt(4) for p<=6, vmcnt(0) at p=7, none after p=8.
//   WAR: buffer (s+2)%3 was last READ at step s-1; those reads complete
//   before the end-of-(s-1) barrier; the overwrite is issued after it.
__global__ __launch_bounds__(256) void gemm_kan(const _Float16* __restrict__ X,
                                                const _Float16* __restrict__ W,
                                                const float* __restrict__ kn,
                                                float* __restrict__ C) {
  constexpr int N = OUT_F;
  __shared__ _Float16 Xs[BM * BK];        // 16 KB, x-tile
  __shared__ _Float16 Ws[3][BN * BK];     // 3 x 16 KB, triple-buffered W plane

  const int tid  = threadIdx.x;
  const int lane = tid & 63;
  const int wv   = tid >> 6;
  const int wm   = wv >> 1;
  const int wn   = wv & 1;

  // XCD-aware decode: xcd = bid&7 owns 2 n-tiles (L2-resident W panel);
  // y (M) sweeps fastest within an XCD.
  const int bid = blockIdx.x;
  const int xcd = bid & 7;
  const int r   = bid >> 3;
  const int y   = r & 31;
  const int x2  = r >> 5;
  const int m0  = y * BM;
  const int n0  = (xcd * 2 + x2) * BN;

  _Float16 kh[8];
#pragma unroll
  for (int j = 0; j < 8; ++j) kh[j] = (_Float16)kn[j];

  f32x16 acc[2][2] = {};   // 2x2 blocks of 32x32 per wave (64x64 tile)

  // staging: 256 thr x 16B = 32 rows/pass, 4 passes. XOR swizzle applied to
  // the GLOBAL chunk (LDS dest must stay base + lane*16 for global_load_lds).
  const int rowS = tid >> 3;                        // 0..31
  const int kgS  = ((tid & 7) ^ (rowS & 7)) * 8;    // swizzled source chunk
  const int ldst = (tid & 7) * 8;                   // LDS chunk

  const _Float16* Wrow = W + kgS;   // + (n0+r2)*KDIM + p*IN_F + i0
  const _Float16* Xrow = X + kgS;   // + (m0+r2)*IN_F + i0

#define STAGE_W(IBX, PP, BUF) { \
    const int off_ = (PP) * IN_F + (IBX) * BK; \
    _Pragma("unroll") \
    for (int p4 = 0; p4 < 4; ++p4) { \
      const int r2 = p4 * 32 + rowS; \
      __builtin_amdgcn_global_load_lds( \
        (const __attribute__((address_space(1))) void*)(Wrow + (size_t)(n0 + r2) * KDIM + off_), \
        (__attribute__((address_space(3))) void*)(Ws[BUF] + r2 * BK + ldst), 16, 0, 0); } }

#define STAGE_X(IBX) { \
    const int off_ = (IBX) * BK; \
    _Pragma("unroll") \
    for (int p4 = 0; p4 < 4; ++p4) { \
      const int r2 = p4 * 32 + rowS; \
      __builtin_amdgcn_global_load_lds( \
        (const __attribute__((address_space(1))) void*)(Xrow + (size_t)(m0 + r2) * IN_F + off_), \
        (__attribute__((address_space(3))) void*)(Xs + r2 * BK + ldst), 16, 0, 0); } }

  // prologue: X(0), W(0,0), W(0,1); leave W(0,1) in flight
  STAGE_X(0);
  STAGE_W(0, 0, 0);
  STAGE_W(0, 1, 1);
  WAITVM(4);
  __builtin_amdgcn_s_barrier();
  __builtin_amdgcn_sched_barrier(0);

  for (int ib = 0; ib < 32; ++ib) {
    const bool notlast = (ib < 31);

    // X fragments for this i-block (Xs dead after these reads).
    // 32x32x16 A-frag: row = lane&31, k = ks*16 + (lane>>5)*8 + j.
    // Swizzled chunk: (ks*2 + (lane>>5)) ^ (row&7), row&7 == lane&7.
    f16x8 xf[2][4];
#pragma unroll
    for (int ks = 0; ks < 4; ++ks) {
      const int koff = ((ks * 2 + (lane >> 5)) ^ (lane & 7)) * 8;
#pragma unroll
      for (int mb = 0; mb < 2; ++mb)
        xf[mb][ks] = *(const f16x8*)(Xs + (wm * 64 + mb * 32 + (lane & 31)) * BK + koff);
    }

#pragma unroll
    for (int p = 0; p < NPLANE; ++p) {
      const int bufc = p % 3;
      const int buf2 = (p + 2) % 3;

      // ---- issue prefetch for step s+2 (never waited here) ----
      if (p < 7) {
        STAGE_W(ib, p + 2, buf2);
      } else if (notlast) {
        STAGE_W(ib + 1, p - 7, buf2);      // p=7 -> (ib+1,0), p=8 -> (ib+1,1)
      }
      if (p == 1 && notlast) STAGE_X(ib + 1);
      __builtin_amdgcn_sched_barrier(0);   // stages issue before compute

      // ---- compute plane p from Ws[bufc] ----
      const _Float16* Wc = Ws[bufc];
      __builtin_amdgcn_s_setprio(1);
#pragma unroll
      for (int ks = 0; ks < 4; ++ks) {
        const int koff = ((ks * 2 + (lane >> 5)) ^ (lane & 7)) * 8;
        f16x8 bfr[2];
#pragma unroll
        for (int nb = 0; nb < 2; ++nb)
          bfr[nb] = *(const f16x8*)(Wc + (wn * 64 + nb * 32 + (lane & 31)) * BK + koff);
        if (p == 0) {
#pragma unroll
          for (int mb = 0; mb < 2; ++mb)
#pragma unroll
            for (int nb = 0; nb < 2; ++nb)
              acc[mb][nb] = __builtin_amdgcn_mfma_f32_32x32x16_f16(xf[mb][ks], bfr[nb],
                                                                   acc[mb][nb], 0, 0, 0);
        } else {
          const _Float16 kg = kh[p - 1];
#pragma unroll
          for (int mb = 0; mb < 2; ++mb) {
            const f16x8 af = relu_shift(xf[mb][ks], kg);
#pragma unroll
            for (int nb = 0; nb < 2; ++nb)
              acc[mb][nb] = __builtin_amdgcn_mfma_f32_32x32x16_f16(af, bfr[nb],
                                                                   acc[mb][nb], 0, 0, 0);
          }
        }
      }
      __builtin_amdgcn_s_setprio(0);

      // ---- counted wait + barrier (never vmcnt(0) except tail) ----
      if (p == 8 && !notlast) {
        // very last step: fall through to epilogue
      } else if (notlast) {
        if (p == 1 || p == 2) { WAITVM(8); } else { WAITVM(4); }
        __builtin_amdgcn_s_barrier();
        __builtin_amdgcn_sched_barrier(0);
      } else {
        if (p <= 6) { WAITVM(4); } else { WAITVM(0); }
        __builtin_amdgcn_s_barrier();
        __builtin_amdgcn_sched_barrier(0);
      }
    }
  }

  // epilogue: 32x32 C/D layout col=lane&31, row=(reg&3)+8*(reg>>2)+4*(lane>>5)
  const int cn = lane & 31;
  const int rb = 4 * (lane >> 5);
#pragma unroll
  for (int mb = 0; mb < 2; ++mb) {
#pragma unroll
    for (int nb = 0; nb < 2; ++nb) {
      const int col = n0 + wn * 64 + nb * 32 + cn;
#pragma unroll
      for (int reg = 0; reg < 16; ++reg) {
        const int row = m0 + wm * 64 + mb * 32 + (reg & 3) + 8 * (reg >> 2) + rb;
        C[(size_t)row * N + col] = acc[mb][nb][reg];
      }
    }
  }
#undef STAGE_W
#undef STAGE_X
}

// ---------------- fallback: fp32, wave per (b,o) ----------------
__global__ __launch_bounds__(256) void kan_naive(const float* __restrict__ x,
                                                 const float* __restrict__ bw,
                                                 const float* __restrict__ sw,
                                                 const float* __restrict__ kn,
                                                 float* __restrict__ out) {
  const int lane = threadIdx.x & 63;
  const int o = blockIdx.x * 4 + (threadIdx.x >> 6);
  const int b = blockIdx.y;
  float k[8];
#pragma unroll
  for (int g = 0; g < 8; ++g) k[g] = kn[g];
  float acc = 0.f;
  for (int i = lane; i < IN_F; i += 64) {
    const float v = x[(size_t)b * IN_F + i];
    float sp = 0.f;
    const float* s = sw + ((size_t)o * IN_F + i) * 8;
#pragma unroll
    for (int g = 0; g < 8; ++g) {
      float r = v - k[g];
      sp += s[g] * (r > 0.f ? r : 0.f);
    }
    acc += v * bw[(size_t)o * IN_F + i] + 0.1f * sp;
  }
#pragma unroll
  for (int off = 32; off; off >>= 1) acc += __shfl_down(acc, off, 64);
  if (lane == 0) out[(size_t)b * OUT_F + o] = acc;
}

extern "C" void kernel_launch(void* const* d_in, const int* in_sizes, int n_in,
                              void* d_out, int out_size, void* d_ws, size_t ws_size,
                              hipStream_t stream) {
  const float* x  = (const float*)d_in[0];
  const float* bw = (const float*)d_in[1];
  const float* sw = (const float*)d_in[2];
  const float* kn = (const float*)d_in[3];
  float* out = (float*)d_out;

  const size_t wbytes = (size_t)OUT_F * KDIM * sizeof(_Float16);   // 75.5 MB
  const size_t xbytes = (size_t)BATCH * IN_F * sizeof(_Float16);   // 16.8 MB

  if (ws_size < wbytes + xbytes) {
    dim3 grid(OUT_F / 4, BATCH);
    kan_naive<<<grid, 256, 0, stream>>>(x, bw, sw, kn, out);
    return;
  }

  _Float16* W = (_Float16*)d_ws;
  _Float16* X = (_Float16*)((char*)d_ws + wbytes);

  prep_X<<<(BATCH * IN_F) / 8 / 256, 256, 0, stream>>>(x, X);
  prep_W<<<OUT_F, 256, 0, stream>>>(bw, sw, W);
  gemm_kan<<<512, 256, 0, stream>>>(X, W, kn, out);
}

// Round 4
// 493.025 us; speedup vs baseline: 1.1288x; 1.1288x over previous
//
#include <hip/hip_runtime.h>
#include <hip/hip_bf16.h>
#include <hip/hip_fp16.h>

// KAN layer = fp16 MFMA GEMM over g-major expanded K: k = p*2048 + i.
// plane p=0: feature x, weight bw; planes p=1..8: feature max(x,kn[p-1]),
// weight 0.1*sw[o,i,p-1], minus precomputed bias[o] = sum_g k_g * sum_i w_g
// (relu(x-k) = max(x,k) - k identity -> halves relu VALU: 4 pk_max vs
// 4 pk_add + 4 pk_max per fragment; subtraction exact in f32 epilogue).
// R7 pipeline (verified 288us, 0 conflicts): triple-buffered W tiles,
// prefetch distance 2, counted vmcnt (never 0 in main loop), raw s_barrier,
// setprio(1) around compute, 16x16x32 MFMA, XOR-swizzled LDS.
// R9: revert R8's 32x32 experiment (introduced 4 conflict-cyc per ds_read);
// apply max-identity + bias instead.
#define BATCH 4096
#define IN_F  2048
#define OUT_F 2048
#define NPLANE 9
#define KDIM  (IN_F * NPLANE)        // 18432
#define MN    ((size_t)BATCH * OUT_F)

typedef __attribute__((ext_vector_type(8))) _Float16 f16x8;
typedef __attribute__((ext_vector_type(2))) _Float16 f16x2;
typedef __attribute__((ext_vector_type(4))) float    f32x4;

#define WAITVM(N) { asm volatile("s_waitcnt vmcnt(" #N ")" ::: "memory"); \
                    __builtin_amdgcn_sched_barrier(0); }

// ---------------- prep: x fp32 -> fp16 image [b][i] ----------------
__global__ __launch_bounds__(256) void prep_X(const float* __restrict__ x,
                                              _Float16* __restrict__ X) {
  const size_t idx = ((size_t)blockIdx.x * 256 + threadIdx.x) * 8;
  const float4* v = (const float4*)(x + idx);
  float4 a = v[0], b = v[1];
  f16x8 o;
  o[0]=(_Float16)a.x; o[1]=(_Float16)a.y; o[2]=(_Float16)a.z; o[3]=(_Float16)a.w;
  o[4]=(_Float16)b.x; o[5]=(_Float16)b.y; o[6]=(_Float16)b.z; o[7]=(_Float16)b.w;
  *(f16x8*)(X + idx) = o;
}

// ---------------- prep: bw + sw -> W image + per-o bias ----------------
// One block per o-row. Thread t owns i in [t*8, t*8+8). Also accumulates
// bias[o] = sum_g kn[g] * sum_i (fp16)(0.1*sw[o,i,g]) — the exact fp16-
// rounded weights the MFMA consumes, so max-identity matches relu path.
__global__ __launch_bounds__(256) void prep_W(const float* __restrict__ bw,
                                              const float* __restrict__ sw,
                                              const float* __restrict__ kn,
                                              _Float16* __restrict__ W,
                                              float* __restrict__ bias) {
  const int o  = blockIdx.x;          // 2048 blocks
  const int i0 = threadIdx.x * 8;     // i-chunk

  const float4* s = (const float4*)(sw + ((size_t)o * IN_F + i0) * 8);
  float4 qv[16];
#pragma unroll
  for (int k = 0; k < 16; ++k) qv[k] = s[k];
  const float* q = (const float*)qv;  // q[j*8 + g] = sw[o, i0+j, g]

  _Float16* base = W + (size_t)o * KDIM + i0;

  // plane 0: base weight
  const float4* b4 = (const float4*)(bw + (size_t)o * IN_F + i0);
  float4 b0 = b4[0], b1 = b4[1];
  f16x8 h0;
  h0[0]=(_Float16)b0.x; h0[1]=(_Float16)b0.y; h0[2]=(_Float16)b0.z; h0[3]=(_Float16)b0.w;
  h0[4]=(_Float16)b1.x; h0[5]=(_Float16)b1.y; h0[6]=(_Float16)b1.z; h0[7]=(_Float16)b1.w;
  *(f16x8*)base = h0;

  // planes 1..8: 0.1 * sw[o, i, g]; accumulate k_g * w per thread
  float part = 0.f;
#pragma unroll
  for (int g = 0; g < 8; ++g) {
    const float kg = kn[g];
    f16x8 h;
    float rs = 0.f;
#pragma unroll
    for (int j = 0; j < 8; ++j) {
      _Float16 v = (_Float16)(0.1f * q[j * 8 + g]);
      h[j] = v;
      rs += (float)v;
    }
    part += kg * rs;
    *(f16x8*)(base + (g + 1) * IN_F) = h;
  }

  // reduce part across 256 threads -> bias[o]
  const int lane = threadIdx.x & 63;
  const int wv   = threadIdx.x >> 6;
#pragma unroll
  for (int off = 32; off; off >>= 1) part += __shfl_down(part, off, 64);
  __shared__ float red[4];
  if (lane == 0) red[wv] = part;
  __syncthreads();
  if (threadIdx.x == 0) bias[o] = red[0] + red[1] + red[2] + red[3];
}

// ---------------- GEMM ----------------
#define BM 128
#define BN 128
#define BK 64

// A-operand for spline planes: max(x, k) (bias handles the -k term).
// 4x v_pk_max_f16 per fragment.
__device__ inline f16x8 max_k(f16x8 x, f16x8 kv) {
  return __builtin_elementwise_max(x, kv);
}

// Pipeline (per wave, 4 global_load_lds per tile):
//   step s = (ib, p) computes plane p from Ws[p%3]; issues tile s+2 into
//   Ws[(p+2)%3]; X(ib+1) issued at p==1 (after plane-0 barrier, Xs dead).
//   End-of-step wait leaves the newest prefetch in flight:
//     steady: vmcnt(4); p=1,2: vmcnt(8) (X group sits in the FIFO);
//     ib=31 tail: vmcnt(4) for p<=6, vmcnt(0) at p=7, none after p=8.
//   WAR: buffer (s+2)%3 was last READ at step s-1; those reads complete
//   before the end-of-(s-1) barrier; the overwrite is issued after it.
__global__ __launch_bounds__(256) void gemm_kan(const _Float16* __restrict__ X,
                                                const _Float16* __restrict__ W,
                                                const float* __restrict__ kn,
                                                const float* __restrict__ bias,
                                                float* __restrict__ C) {
  constexpr int N = OUT_F;
  __shared__ _Float16 Xs[BM * BK];        // 16 KB, x-tile
  __shared__ _Float16 Ws[3][BN * BK];     // 3 x 16 KB, triple-buffered W plane

  const int tid  = threadIdx.x;
  const int lane = tid & 63;
  const int wv   = tid >> 6;
  const int wm   = wv >> 1;
  const int wn   = wv & 1;

  // XCD-aware decode: xcd = bid&7 owns 2 n-tiles (L2-resident W panel);
  // y (M) sweeps fastest within an XCD.
  const int bid = blockIdx.x;
  const int xcd = bid & 7;
  const int r   = bid >> 3;
  const int y   = r & 31;
  const int x2  = r >> 5;
  const int m0  = y * BM;
  const int n0  = (xcd * 2 + x2) * BN;

  // splat knots into f16x8 (regalloc CSEs the repeated halves)
  f16x8 kv8[8];
#pragma unroll
  for (int j = 0; j < 8; ++j) {
    const _Float16 kg = (_Float16)kn[j];
#pragma unroll
    for (int e = 0; e < 8; ++e) kv8[j][e] = kg;
  }

  f32x4 acc[4][4] = {};

  // staging: 256 thr x 16B = 32 rows/pass, 4 passes. XOR swizzle applied to
  // the GLOBAL chunk (LDS dest must stay base + lane*16 for global_load_lds).
  const int rowS = tid >> 3;                        // 0..31
  const int kgS  = ((tid & 7) ^ (rowS & 7)) * 8;    // swizzled source chunk
  const int ldst = (tid & 7) * 8;                   // LDS chunk

  const _Float16* Wrow = W + kgS;   // + (n0+r2)*KDIM + p*IN_F + i0
  const _Float16* Xrow = X + kgS;   // + (m0+r2)*IN_F + i0

#define STAGE_W(IBX, PP, BUF) { \
    const int off_ = (PP) * IN_F + (IBX) * BK; \
    _Pragma("unroll") \
    for (int p4 = 0; p4 < 4; ++p4) { \
      const int r2 = p4 * 32 + rowS; \
      __builtin_amdgcn_global_load_lds( \
        (const __attribute__((address_space(1))) void*)(Wrow + (size_t)(n0 + r2) * KDIM + off_), \
        (__attribute__((address_space(3))) void*)(Ws[BUF] + r2 * BK + ldst), 16, 0, 0); } }

#define STAGE_X(IBX) { \
    const int off_ = (IBX) * BK; \
    _Pragma("unroll") \
    for (int p4 = 0; p4 < 4; ++p4) { \
      const int r2 = p4 * 32 + rowS; \
      __builtin_amdgcn_global_load_lds( \
        (const __attribute__((address_space(1))) void*)(Xrow + (size_t)(m0 + r2) * IN_F + off_), \
        (__attribute__((address_space(3))) void*)(Xs + r2 * BK + ldst), 16, 0, 0); } }

  // prologue: X(0), W(0,0), W(0,1); leave W(0,1) in flight
  STAGE_X(0);
  STAGE_W(0, 0, 0);
  STAGE_W(0, 1, 1);
  WAITVM(4);
  __builtin_amdgcn_s_barrier();
  __builtin_amdgcn_sched_barrier(0);

  for (int ib = 0; ib < 32; ++ib) {
    const bool notlast = (ib < 31);

    // X fragments for this i-block (Xs is dead afterwards)
    f16x8 xf[4][2];
#pragma unroll
    for (int s = 0; s < 2; ++s) {
      const int koff = (((s * 4) + (lane >> 4)) ^ (lane & 7)) * 8;
#pragma unroll
      for (int mi = 0; mi < 4; ++mi)
        xf[mi][s] = *(const f16x8*)(Xs + (wm * 64 + mi * 16 + (lane & 15)) * BK + koff);
    }

#pragma unroll
    for (int p = 0; p < NPLANE; ++p) {
      const int bufc = p % 3;
      const int buf2 = (p + 2) % 3;

      // ---- issue prefetch for step s+2 (never waited here) ----
      if (p < 7) {
        STAGE_W(ib, p + 2, buf2);
      } else if (notlast) {
        STAGE_W(ib + 1, p - 7, buf2);      // p=7 -> (ib+1,0), p=8 -> (ib+1,1)
      }
      if (p == 1 && notlast) STAGE_X(ib + 1);
      __builtin_amdgcn_sched_barrier(0);   // stages issue before compute

      // ---- compute plane p from Ws[bufc] ----
      const _Float16* Wc = Ws[bufc];
      __builtin_amdgcn_s_setprio(1);
#pragma unroll
      for (int s = 0; s < 2; ++s) {
        const int koff = (((s * 4) + (lane >> 4)) ^ (lane & 7)) * 8;
        f16x8 bfr[4];
#pragma unroll
        for (int ni = 0; ni < 4; ++ni)
          bfr[ni] = *(const f16x8*)(Wc + (wn * 64 + ni * 16 + (lane & 15)) * BK + koff);
        if (p == 0) {
#pragma unroll
          for (int mi = 0; mi < 4; ++mi)
#pragma unroll
            for (int ni = 0; ni < 4; ++ni)
              acc[mi][ni] = __builtin_amdgcn_mfma_f32_16x16x32_f16(xf[mi][s], bfr[ni],
                                                                   acc[mi][ni], 0, 0, 0);
        } else {
#pragma unroll
          for (int mi = 0; mi < 4; ++mi) {
            const f16x8 af = max_k(xf[mi][s], kv8[p - 1]);
#pragma unroll
            for (int ni = 0; ni < 4; ++ni)
              acc[mi][ni] = __builtin_amdgcn_mfma_f32_16x16x32_f16(af, bfr[ni],
                                                                   acc[mi][ni], 0, 0, 0);
          }
        }
      }
      __builtin_amdgcn_s_setprio(0);

      // ---- counted wait + barrier (never vmcnt(0) except tail) ----
      if (p == 8 && !notlast) {
        // very last step: fall through to epilogue
      } else if (notlast) {
        if (p == 1 || p == 2) { WAITVM(8); } else { WAITVM(4); }
        __builtin_amdgcn_s_barrier();
        __builtin_amdgcn_sched_barrier(0);
      } else {
        if (p <= 6) { WAITVM(4); } else { WAITVM(0); }
        __builtin_amdgcn_s_barrier();
        __builtin_amdgcn_sched_barrier(0);
      }
    }
  }

  // epilogue: C/D layout col=lane&15, row=(lane>>4)*4+reg; subtract bias[col]
  const int cn = lane & 15;
  const int r4 = (lane >> 4) * 4;
#pragma unroll
  for (int mi = 0; mi < 4; ++mi) {
    const int rowb = m0 + wm * 64 + mi * 16 + r4;
#pragma unroll
    for (int ni = 0; ni < 4; ++ni) {
      const int col = n0 + wn * 64 + ni * 16 + cn;
      const float bcol = bias[col];
#pragma unroll
      for (int reg = 0; reg < 4; ++reg)
        C[(size_t)(rowb + reg) * N + col] = acc[mi][ni][reg] - bcol;
    }
  }
#undef STAGE_W
#undef STAGE_X
}

// ---------------- fallback: fp32, wave per (b,o) ----------------
__global__ __launch_bounds__(256) void kan_naive(const float* __restrict__ x,
                                                 const float* __restrict__ bw,
                                                 const float* __restrict__ sw,
                                                 const float* __restrict__ kn,
                                                 float* __restrict__ out) {
  const int lane = threadIdx.x & 63;
  const int o = blockIdx.x * 4 + (threadIdx.x >> 6);
  const int b = blockIdx.y;
  float k[8];
#pragma unroll
  for (int g = 0; g < 8; ++g) k[g] = kn[g];
  float acc = 0.f;
  for (int i = lane; i < IN_F; i += 64) {
    const float v = x[(size_t)b * IN_F + i];
    float sp = 0.f;
    const float* s = sw + ((size_t)o * IN_F + i) * 8;
#pragma unroll
    for (int g = 0; g < 8; ++g) {
      float r = v - k[g];
      sp += s[g] * (r > 0.f ? r : 0.f);
    }
    acc += v * bw[(size_t)o * IN_F + i] + 0.1f * sp;
  }
#pragma unroll
  for (int off = 32; off; off >>= 1) acc += __shfl_down(acc, off, 64);
  if (lane == 0) out[(size_t)b * OUT_F + o] = acc;
}

extern "C" void kernel_launch(void* const* d_in, const int* in_sizes, int n_in,
                              void* d_out, int out_size, void* d_ws, size_t ws_size,
                              hipStream_t stream) {
  const float* x  = (const float*)d_in[0];
  const float* bw = (const float*)d_in[1];
  const float* sw = (const float*)d_in[2];
  const float* kn = (const float*)d_in[3];
  float* out = (float*)d_out;

  const size_t wbytes = (size_t)OUT_F * KDIM * sizeof(_Float16);   // 75.5 MB
  const size_t xbytes = (size_t)BATCH * IN_F * sizeof(_Float16);   // 16.8 MB
  const size_t bbytes = (size_t)OUT_F * sizeof(float);             // 8 KB

  if (ws_size < wbytes + xbytes + bbytes) {
    dim3 grid(OUT_F / 4, BATCH);
    kan_naive<<<grid, 256, 0, stream>>>(x, bw, sw, kn, out);
    return;
  }

  _Float16* W = (_Float16*)d_ws;
  _Float16* X = (_Float16*)((char*)d_ws + wbytes);
  float* bias = (float*)((char*)d_ws + wbytes + xbytes);

  prep_X<<<(BATCH * IN_F) / 8 / 256, 256, 0, stream>>>(x, X);
  prep_W<<<OUT_F, 256, 0, stream>>>(bw, sw, kn, W, bias);
  gemm_kan<<<512, 256, 0, stream>>>(X, W, kn, bias, out);
}